// Round 1
// baseline (242.152 us; speedup 1.0000x reference)
//
#include <hip/hip_runtime.h>
#include <hip/hip_bf16.h>

// Relative (Transformer-XL) multi-head attention, MI355X gfx950.
// B=8, T=1024, H=8, d=64, D_MODEL=512, W=2047. Output f32.
//
// Pipeline:
//   1. cvt f32->bf16: x, pos_emb; cvt+transpose weights (N x K layout)
//   2. MFMA GEMM: q = x@Wq+bq, k = x@Wk, v = x@Wv, p = pos_emb@Wp (bf16 out)
//   3. fused flash attention with relative-shift handled as a gathered
//      64x128 pos-window GEMM; u/v folded in as rank-1 score biases
//   4. MFMA GEMM: out = attn@Wo + bo (f32 out)

typedef __attribute__((ext_vector_type(8))) short short8;
typedef __attribute__((ext_vector_type(4))) float float4v;

#define NB_T 1024
#define NB_H 8
#define NB_D 64
#define NB_DM 512
#define NB_W 2047

__device__ __forceinline__ unsigned short f2bf(float f) {
  union { float f; unsigned u; } x; x.f = f;
  unsigned r = x.u + 0x7FFFu + ((x.u >> 16) & 1u);
  return (unsigned short)(r >> 16);
}
__device__ __forceinline__ float bf2f(unsigned short b) {
  union { unsigned u; float f; } x; x.u = ((unsigned)b) << 16;
  return x.f;
}

// ---------- conversion kernels ----------
__global__ void cvt_bf16_kernel(const float* __restrict__ in,
                                unsigned short* __restrict__ out, int n4) {
  int i = blockIdx.x * blockDim.x + threadIdx.x;
  if (i < n4) {
    float4 f = ((const float4*)in)[i];
    ushort4 r;
    r.x = f2bf(f.x); r.y = f2bf(f.y); r.z = f2bf(f.z); r.w = f2bf(f.w);
    ((ushort4*)out)[i] = r;
  }
}

// 512x512: wt[n][k] = w[k][n]  (bf16)
__global__ void transpose_cvt_kernel(const float* __restrict__ w,
                                     unsigned short* __restrict__ wt) {
  int idx = blockIdx.x * 256 + threadIdx.x;   // exactly 262144 threads
  int kk = idx >> 9, n = idx & 511;
  wt[(n << 9) | kk] = f2bf(w[idx]);
}

// ---------- generic bf16 MFMA GEMM:  C[M x 512] = A[M x 512] @ Bt^T (+bias) ----------
// A row-major bf16, Bt is (N=512 x K=512) row-major bf16 (i.e. B transposed).
__global__ __launch_bounds__(256) void gemm_kernel(
    const unsigned short* __restrict__ A,
    const unsigned short* __restrict__ Bt,
    const float* __restrict__ bias,          // nullptr ok
    unsigned short* __restrict__ Cb,         // bf16 out (if !f32out)
    float* __restrict__ Cf,                  // f32 out (if f32out)
    int M, int f32out) {
  __shared__ __align__(16) unsigned short As[64][72];
  __shared__ __align__(16) unsigned short Bs[64][72];
  int mt = blockIdx.x, nt = blockIdx.y;
  int tid = threadIdx.x;
  int lr = tid >> 2;              // 0..63
  int lc = (tid & 3) << 4;        // 0,16,32,48
  int lane = tid & 63, wave = tid >> 6;

  int arow = mt * 64 + lr; if (arow >= M) arow = M - 1;   // clamp (M=2047 case)
  const unsigned short* Ap = A + (size_t)arow * 512 + lc;
  const unsigned short* Bp = Bt + (size_t)(nt * 64 + lr) * 512 + lc;

  float4v acc[4] = {};
  for (int kt = 0; kt < 8; ++kt) {
    __syncthreads();
    *(uint4*)&As[lr][lc]     = *(const uint4*)(Ap + kt * 64);
    *(uint4*)&As[lr][lc + 8] = *(const uint4*)(Ap + kt * 64 + 8);
    *(uint4*)&Bs[lr][lc]     = *(const uint4*)(Bp + kt * 64);
    *(uint4*)&Bs[lr][lc + 8] = *(const uint4*)(Bp + kt * 64 + 8);
    __syncthreads();
#pragma unroll
    for (int ks = 0; ks < 2; ++ks) {
      short8 a = *(const short8*)&As[wave * 16 + (lane & 15)][ks * 32 + (lane >> 4) * 8];
#pragma unroll
      for (int fn = 0; fn < 4; ++fn) {
        short8 b = *(const short8*)&Bs[fn * 16 + (lane & 15)][ks * 32 + (lane >> 4) * 8];
        acc[fn] = __builtin_amdgcn_mfma_f32_16x16x32_bf16(a, b, acc[fn], 0, 0, 0);
      }
    }
  }
  int rbase = mt * 64 + wave * 16 + ((lane >> 4) << 2);
  int cb = nt * 64 + (lane & 15);
#pragma unroll
  for (int fn = 0; fn < 4; ++fn) {
    int col = cb + fn * 16;
    float bs = bias ? bias[col] : 0.0f;
#pragma unroll
    for (int r = 0; r < 4; ++r) {
      int row = rbase + r;
      if (row < M) {
        float val = acc[fn][r] + bs;
        if (f32out) Cf[(size_t)row * 512 + col] = val;
        else        Cb[(size_t)row * 512 + col] = f2bf(val);
      }
    }
  }
}

// ---------- fused relative attention ----------
// grid: (16 ti-tiles, 8 heads, 8 batch), 256 threads (4 waves x 16 rows each)
__global__ __launch_bounds__(256) void attn_kernel(
    const unsigned short* __restrict__ Q,   // (B*T, 512) bf16, bias already added
    const unsigned short* __restrict__ K,
    const unsigned short* __restrict__ V,
    const unsigned short* __restrict__ P,   // (2047, 512) bf16
    const float* __restrict__ uvec,         // (8,64)
    const float* __restrict__ vvec,         // (8,64)
    unsigned short* __restrict__ O) {       // (B*T, 512) bf16
  __shared__ __align__(16) unsigned short q_s[64][72];
  __shared__ __align__(16) unsigned short k_s[64][72];
  __shared__ __align__(16) unsigned short vt_s[64][72];
  // p_s: dual-use. Phase A: pos window [128 rows][stride 72].
  // Phase B (after barrier): pos_raw+P stage [64 rows][stride 136].
  __shared__ __align__(16) unsigned short p_s[128 * 72];
  __shared__ float uk_s[64], vp_s[128], us_s[64], vs_s[64];

  int tt = blockIdx.x, h = blockIdx.y, b = blockIdx.z;
  int t0 = tt * 64;
  int tid = threadIdx.x, lane = tid & 63, wave = tid >> 6;
  int lr = tid >> 2, lc = (tid & 3) << 4;
  int rowg = (lane >> 4) << 2;              // 0,4,8,12

  // stage q tile (held for whole block) + u,v vectors
  {
    const unsigned short* qb = Q + (size_t)(b * NB_T + t0 + lr) * 512 + h * 64 + lc;
    *(uint4*)&q_s[lr][lc]     = *(const uint4*)qb;
    *(uint4*)&q_s[lr][lc + 8] = *(const uint4*)(qb + 8);
    if (tid < 64)       us_s[tid]      = uvec[h * 64 + tid];
    else if (tid < 128) vs_s[tid - 64] = vvec[h * 64 + tid - 64];
  }
  __syncthreads();

  short8 aq[2];
  aq[0] = *(const short8*)&q_s[wave * 16 + (lane & 15)][(lane >> 4) * 8];
  aq[1] = *(const short8*)&q_s[wave * 16 + (lane & 15)][32 + (lane >> 4) * 8];

  float4v accO[4] = {};
  float m_r[4] = {-1e30f, -1e30f, -1e30f, -1e30f};
  float l_r[4] = {0.f, 0.f, 0.f, 0.f};

  for (int st = 0; st < 16; ++st) {
    int s0 = st * 64;
    int w0 = s0 - t0 + 960;                 // first staged p row; in [0,1920]
    __syncthreads();                        // prev-iter LDS reads complete
    // stage K tile
    const unsigned short* kb = K + (size_t)(b * NB_T + s0 + lr) * 512 + h * 64 + lc;
    *(uint4*)&k_s[lr][lc]     = *(const uint4*)kb;
    *(uint4*)&k_s[lr][lc + 8] = *(const uint4*)(kb + 8);
    // stage V tile transposed: vt_s[d][s]
    {
      const unsigned short* vb = V + (size_t)(b * NB_T + s0 + lr) * 512 + h * 64 + lc;
      uint4 v0 = *(const uint4*)vb, v1 = *(const uint4*)(vb + 8);
      unsigned short tmp[16];
      *(uint4*)tmp = v0; *(uint4*)(tmp + 8) = v1;
#pragma unroll
      for (int j = 0; j < 16; ++j) vt_s[lc + j][lr] = tmp[j];
    }
    // stage p window: 128 rows x 64 (row clamp: row w0+127 is never consumed)
    {
      int r2 = tid >> 1, c2 = (tid & 1) << 5;
      int wr = w0 + r2; if (wr > NB_W - 1) wr = NB_W - 1;
      const unsigned short* pb = P + (size_t)wr * 512 + h * 64 + c2;
      *(uint4*)&p_s[r2 * 72 + c2]      = *(const uint4*)pb;
      *(uint4*)&p_s[r2 * 72 + c2 + 8]  = *(const uint4*)(pb + 8);
      *(uint4*)&p_s[r2 * 72 + c2 + 16] = *(const uint4*)(pb + 16);
      *(uint4*)&p_s[r2 * 72 + c2 + 24] = *(const uint4*)(pb + 24);
    }
    __syncthreads();

    // rank-1 bias terms: uk[s] = u.k_s , vp[j] = v.p_row
    if (tid < 64) {
      float s = 0.f;
      for (int d = 0; d < 64; ++d) s += us_s[d] * bf2f(k_s[tid][d]);
      uk_s[tid] = s;
    } else if (tid < 192) {
      int j = tid - 64;
      float s = 0.f;
      for (int d = 0; d < 64; ++d) s += vs_s[d] * bf2f(p_s[j * 72 + d]);
      vp_s[j] = s;
    }

    // content (64x64) and pos-window (64x128) score MFMAs
    float4v accS[4] = {}; float4v accP[8] = {};
#pragma unroll
    for (int ks = 0; ks < 2; ++ks) {
#pragma unroll
      for (int fn = 0; fn < 4; ++fn) {
        short8 bk = *(const short8*)&k_s[fn * 16 + (lane & 15)][ks * 32 + (lane >> 4) * 8];
        accS[fn] = __builtin_amdgcn_mfma_f32_16x16x32_bf16(aq[ks], bk, accS[fn], 0, 0, 0);
      }
#pragma unroll
      for (int fn = 0; fn < 8; ++fn) {
        short8 bp = *(const short8*)&p_s[(fn * 16 + (lane & 15)) * 72 + ks * 32 + (lane >> 4) * 8];
        accP[fn] = __builtin_amdgcn_mfma_f32_16x16x32_bf16(aq[ks], bp, accP[fn], 0, 0, 0);
      }
    }
    __syncthreads();   // window reads done everywhere; uk/vp visible

    // stage pos_raw into p_s (stride-136 layout); wave-disjoint rows
#pragma unroll
    for (int fn = 0; fn < 8; ++fn)
#pragma unroll
      for (int r = 0; r < 4; ++r)
        p_s[(wave * 16 + rowg + r) * 136 + fn * 16 + (lane & 15)] = f2bf(accP[fn][r]);

    // combine + online softmax (wave-local from here on)
    float pvals[4][4]; float alpha[4];
#pragma unroll
    for (int r = 0; r < 4; ++r) {
      int tl = wave * 16 + rowg + r;        // block-local ti
      float sc[4]; float rowmax = -1e30f;
#pragma unroll
      for (int fn = 0; fn < 4; ++fn) {
        int si = fn * 16 + (lane & 15);
        int j = si - tl + 63;               // 0..126
        float s = (accS[fn][r] + uk_s[si] + bf2f(p_s[tl * 136 + j]) + vp_s[j]) * 0.125f;
        sc[fn] = s;
        rowmax = fmaxf(rowmax, s);
      }
      rowmax = fmaxf(rowmax, __shfl_xor(rowmax, 1));
      rowmax = fmaxf(rowmax, __shfl_xor(rowmax, 2));
      rowmax = fmaxf(rowmax, __shfl_xor(rowmax, 4));
      rowmax = fmaxf(rowmax, __shfl_xor(rowmax, 8));
      float mnew = fmaxf(m_r[r], rowmax);
      float al = __expf(m_r[r] - mnew);
      float rs = 0.f;
#pragma unroll
      for (int fn = 0; fn < 4; ++fn) {
        float e = __expf(sc[fn] - mnew);
        pvals[fn][r] = e;
        rs += e;
      }
      rs += __shfl_xor(rs, 1); rs += __shfl_xor(rs, 2);
      rs += __shfl_xor(rs, 4); rs += __shfl_xor(rs, 8);
      l_r[r] = l_r[r] * al + rs;
      m_r[r] = mnew;
      alpha[r] = al;
    }
#pragma unroll
    for (int fn = 0; fn < 4; ++fn)
#pragma unroll
      for (int r = 0; r < 4; ++r) accO[fn][r] *= alpha[r];

    // stage P (bf16) into cols 0..63 of own rows (stride 136) — wave-local
#pragma unroll
    for (int fn = 0; fn < 4; ++fn)
#pragma unroll
      for (int r = 0; r < 4; ++r)
        p_s[(wave * 16 + rowg + r) * 136 + fn * 16 + (lane & 15)] = f2bf(pvals[fn][r]);

    // PV: accO += P @ V   (B-frag from vt_s = V^T)
#pragma unroll
    for (int ks = 0; ks < 2; ++ks) {
      short8 ap = *(const short8*)&p_s[(wave * 16 + (lane & 15)) * 136 + ks * 32 + (lane >> 4) * 8];
#pragma unroll
      for (int fn = 0; fn < 4; ++fn) {
        short8 bv = *(const short8*)&vt_s[fn * 16 + (lane & 15)][ks * 32 + (lane >> 4) * 8];
        accO[fn] = __builtin_amdgcn_mfma_f32_16x16x32_bf16(ap, bv, accO[fn], 0, 0, 0);
      }
    }
  }

  // epilogue: O / l -> bf16
#pragma unroll
  for (int fn = 0; fn < 4; ++fn) {
    int dcol = fn * 16 + (lane & 15);
#pragma unroll
    for (int r = 0; r < 4; ++r) {
      int row = t0 + wave * 16 + rowg + r;
      float o = accO[fn][r] / l_r[r];
      O[(size_t)(b * NB_T + row) * 512 + h * 64 + dcol] = f2bf(o);
    }
  }
}

// ---------- host ----------
extern "C" void kernel_launch(void* const* d_in, const int* in_sizes, int n_in,
                              void* d_out, int out_size, void* d_ws, size_t ws_size,
                              hipStream_t stream) {
  const float* x       = (const float*)d_in[0];
  const float* pos_emb = (const float*)d_in[1];
  const float* Wq      = (const float*)d_in[2];
  const float* bq      = (const float*)d_in[3];
  const float* Wk      = (const float*)d_in[4];
  const float* Wv      = (const float*)d_in[5];
  const float* Wp      = (const float*)d_in[6];
  const float* Wo      = (const float*)d_in[7];
  const float* bo      = (const float*)d_in[8];
  const float* u       = (const float*)d_in[9];
  const float* v       = (const float*)d_in[10];

  char* ws = (char*)d_ws;
  unsigned short* xb   = (unsigned short*)ws; ws += (size_t)8192 * 512 * 2;
  unsigned short* peb  = (unsigned short*)ws; ws += (size_t)2048 * 512 * 2;
  unsigned short* wqt  = (unsigned short*)ws; ws += (size_t)512 * 512 * 2;
  unsigned short* wkt  = (unsigned short*)ws; ws += (size_t)512 * 512 * 2;
  unsigned short* wvt  = (unsigned short*)ws; ws += (size_t)512 * 512 * 2;
  unsigned short* wpt  = (unsigned short*)ws; ws += (size_t)512 * 512 * 2;
  unsigned short* wot  = (unsigned short*)ws; ws += (size_t)512 * 512 * 2;
  unsigned short* qb   = (unsigned short*)ws; ws += (size_t)8192 * 512 * 2;
  unsigned short* kb   = (unsigned short*)ws; ws += (size_t)8192 * 512 * 2;
  unsigned short* vb   = (unsigned short*)ws; ws += (size_t)8192 * 512 * 2;
  unsigned short* pb   = (unsigned short*)ws; ws += (size_t)2048 * 512 * 2;
  unsigned short* attb = (unsigned short*)ws; ws += (size_t)8192 * 512 * 2;

  // conversions
  cvt_bf16_kernel<<<4096, 256, 0, stream>>>(x, xb, 1048576);          // 8192*512/4
  cvt_bf16_kernel<<<1024, 256, 0, stream>>>(pos_emb, peb, 262016);    // 2047*512/4
  transpose_cvt_kernel<<<1024, 256, 0, stream>>>(Wq, wqt);
  transpose_cvt_kernel<<<1024, 256, 0, stream>>>(Wk, wkt);
  transpose_cvt_kernel<<<1024, 256, 0, stream>>>(Wv, wvt);
  transpose_cvt_kernel<<<1024, 256, 0, stream>>>(Wp, wpt);
  transpose_cvt_kernel<<<1024, 256, 0, stream>>>(Wo, wot);

  // projections
  gemm_kernel<<<dim3(128, 8), 256, 0, stream>>>(xb,  wqt, bq,      qb, nullptr, 8192, 0);
  gemm_kernel<<<dim3(128, 8), 256, 0, stream>>>(xb,  wkt, nullptr, kb, nullptr, 8192, 0);
  gemm_kernel<<<dim3(128, 8), 256, 0, stream>>>(xb,  wvt, nullptr, vb, nullptr, 8192, 0);
  gemm_kernel<<<dim3(32, 8),  256, 0, stream>>>(peb, wpt, nullptr, pb, nullptr, 2047, 0);

  // fused attention
  attn_kernel<<<dim3(16, 8, 8), 256, 0, stream>>>(qb, kb, vb, pb, u, v, attb);

  // output projection (f32 out)
  gemm_kernel<<<dim3(128, 8), 256, 0, stream>>>(attb, wot, bo, nullptr, (float*)d_out, 8192, 1);
}

// Round 2
// 189.097 us; speedup vs baseline: 1.2806x; 1.2806x over previous
//
#include <hip/hip_runtime.h>
#include <hip/hip_bf16.h>

// Relative (Transformer-XL) multi-head attention, MI355X gfx950.
// B=8, T=1024, H=8, d=64, D_MODEL=512, W=2047. Output f32.
//
// Round 2:
//  - u,v folded into Q at projection time (QU=q+bq+u, QV=q+bq+v) -> no rank-1
//    dot loops in attention
//  - merged QKV projection GEMM (grid 128x24); V written transposed globally
//  - attention: Q frags straight from global (no q LDS), vectorized V^T stage,
//    XOR-swizzled pos_raw/P staging (conflict-free scalar phase)
//  - LDS 36.9KB -> 4 blocks/CU, grid 1024 fully resident

typedef __attribute__((ext_vector_type(8))) short short8;
typedef __attribute__((ext_vector_type(4))) float float4v;

__device__ __forceinline__ unsigned short f2bf(float f) {
  union { float f; unsigned u; } x; x.f = f;
  unsigned r = x.u + 0x7FFFu + ((x.u >> 16) & 1u);
  return (unsigned short)(r >> 16);
}
__device__ __forceinline__ float bf2f(unsigned short b) {
  union { unsigned u; float f; } x; x.u = ((unsigned)b) << 16;
  return x.f;
}

// ---------- conversion kernels ----------
__global__ void cvt_bf16_kernel(const float* __restrict__ in,
                                unsigned short* __restrict__ out, int n4) {
  int i = blockIdx.x * blockDim.x + threadIdx.x;
  if (i < n4) {
    float4 f = ((const float4*)in)[i];
    ushort4 r;
    r.x = f2bf(f.x); r.y = f2bf(f.y); r.z = f2bf(f.z); r.w = f2bf(f.w);
    ((ushort4*)out)[i] = r;
  }
}

// 5x 512x512 transposes in one launch: dst is 5 contiguous 512x512 bf16 mats
__global__ void transpose_cvt5_kernel(const float* __restrict__ Wq,
                                      const float* __restrict__ Wk,
                                      const float* __restrict__ Wv,
                                      const float* __restrict__ Wp,
                                      const float* __restrict__ Wo,
                                      unsigned short* __restrict__ dst) {
  int y = blockIdx.y;
  const float* w = (y == 0) ? Wq : (y == 1) ? Wk : (y == 2) ? Wv : (y == 3) ? Wp : Wo;
  unsigned short* wt = dst + (size_t)y * 262144;
  int idx = blockIdx.x * 256 + threadIdx.x;
  int kk = idx >> 9, n = idx & 511;
  wt[(n << 9) | kk] = f2bf(w[idx]);
}

// ---------- merged QKV projection GEMM ----------
// A = xb (8192x512 bf16), Bt = combined [Wq;Wk;Wv]^T (1536x512 bf16).
// nt 0..7: Q tile -> QU = q+bq+u, QV = q+bq+v (bf16)
// nt 8..15: K tile -> Kb
// nt 16..23: V tile -> written TRANSPOSED to Vt[b][h][d][s]
__global__ __launch_bounds__(256) void qkv_gemm_kernel(
    const unsigned short* __restrict__ A,
    const unsigned short* __restrict__ Bt,
    const float* __restrict__ bq,
    const float* __restrict__ uvec,   // 512 floats (8x64 flat)
    const float* __restrict__ vvec,
    unsigned short* __restrict__ QU, unsigned short* __restrict__ QV,
    unsigned short* __restrict__ Kb, unsigned short* __restrict__ Vt) {
  __shared__ __align__(16) unsigned short As[64][72];
  __shared__ __align__(16) unsigned short Bs[64][72];
  int mt = blockIdx.x, nt = blockIdx.y;
  int tid = threadIdx.x;
  int lr = tid >> 2, lc = (tid & 3) << 4;
  int lane = tid & 63, wave = tid >> 6;
  int l15 = lane & 15, g = lane >> 4;

  const unsigned short* Ap = A + (size_t)(mt * 64 + lr) * 512 + lc;
  const unsigned short* Bp = Bt + (size_t)(nt * 64 + lr) * 512 + lc;

  float4v acc[4] = {};
  for (int kt = 0; kt < 8; ++kt) {
    __syncthreads();
    *(uint4*)&As[lr][lc]     = *(const uint4*)(Ap + kt * 64);
    *(uint4*)&As[lr][lc + 8] = *(const uint4*)(Ap + kt * 64 + 8);
    *(uint4*)&Bs[lr][lc]     = *(const uint4*)(Bp + kt * 64);
    *(uint4*)&Bs[lr][lc + 8] = *(const uint4*)(Bp + kt * 64 + 8);
    __syncthreads();
#pragma unroll
    for (int ks = 0; ks < 2; ++ks) {
      short8 a = *(const short8*)&As[wave * 16 + l15][ks * 32 + g * 8];
#pragma unroll
      for (int fn = 0; fn < 4; ++fn) {
        short8 b = *(const short8*)&Bs[fn * 16 + l15][ks * 32 + g * 8];
        acc[fn] = __builtin_amdgcn_mfma_f32_16x16x32_bf16(a, b, acc[fn], 0, 0, 0);
      }
    }
  }
  int rl = wave * 16 + ((lane >> 4) << 2);         // local row base
  if (nt < 8) {
#pragma unroll
    for (int fn = 0; fn < 4; ++fn) {
      int col = nt * 64 + fn * 16 + l15;
      float bs = bq[col], uu = uvec[col], vv = vvec[col];
#pragma unroll
      for (int r = 0; r < 4; ++r) {
        size_t idx = (size_t)(mt * 64 + rl + r) * 512 + col;
        float base = acc[fn][r] + bs;
        QU[idx] = f2bf(base + uu);
        QV[idx] = f2bf(base + vv);
      }
    }
  } else if (nt < 16) {
#pragma unroll
    for (int fn = 0; fn < 4; ++fn) {
      int col = (nt - 8) * 64 + fn * 16 + l15;
#pragma unroll
      for (int r = 0; r < 4; ++r)
        Kb[(size_t)(mt * 64 + rl + r) * 512 + col] = f2bf(acc[fn][r]);
    }
  } else {
    // transpose 64x64 tile through As, write coalesced to Vt[b][h][d][s]
    __syncthreads();
#pragma unroll
    for (int fn = 0; fn < 4; ++fn)
#pragma unroll
      for (int r = 0; r < 4; ++r)
        As[rl + r][fn * 16 + l15] = f2bf(acc[fn][r]);
    __syncthreads();
    int d = tid >> 2, sc = (tid & 3) * 16;
    int bb = mt >> 4, s0 = (mt & 15) * 64, h = nt - 16;
    unsigned short tmp[16];
#pragma unroll
    for (int j = 0; j < 16; ++j) tmp[j] = As[sc + j][d];
    unsigned short* op = Vt + ((size_t)((bb * 8 + h) * 64 + d)) * 1024 + s0 + sc;
    *(uint4*)op       = *(uint4*)tmp;
    *(uint4*)(op + 8) = *(uint4*)(tmp + 8);
  }
}

// ---------- generic bf16 MFMA GEMM (pos projection, out projection) ----------
__global__ __launch_bounds__(256) void gemm_kernel(
    const unsigned short* __restrict__ A,
    const unsigned short* __restrict__ Bt,
    const float* __restrict__ bias,
    unsigned short* __restrict__ Cb,
    float* __restrict__ Cf,
    int M, int f32out) {
  __shared__ __align__(16) unsigned short As[64][72];
  __shared__ __align__(16) unsigned short Bs[64][72];
  int mt = blockIdx.x, nt = blockIdx.y;
  int tid = threadIdx.x;
  int lr = tid >> 2, lc = (tid & 3) << 4;
  int lane = tid & 63, wave = tid >> 6;

  int arow = mt * 64 + lr; if (arow >= M) arow = M - 1;
  const unsigned short* Ap = A + (size_t)arow * 512 + lc;
  const unsigned short* Bp = Bt + (size_t)(nt * 64 + lr) * 512 + lc;

  float4v acc[4] = {};
  for (int kt = 0; kt < 8; ++kt) {
    __syncthreads();
    *(uint4*)&As[lr][lc]     = *(const uint4*)(Ap + kt * 64);
    *(uint4*)&As[lr][lc + 8] = *(const uint4*)(Ap + kt * 64 + 8);
    *(uint4*)&Bs[lr][lc]     = *(const uint4*)(Bp + kt * 64);
    *(uint4*)&Bs[lr][lc + 8] = *(const uint4*)(Bp + kt * 64 + 8);
    __syncthreads();
#pragma unroll
    for (int ks = 0; ks < 2; ++ks) {
      short8 a = *(const short8*)&As[wave * 16 + (lane & 15)][ks * 32 + (lane >> 4) * 8];
#pragma unroll
      for (int fn = 0; fn < 4; ++fn) {
        short8 b = *(const short8*)&Bs[fn * 16 + (lane & 15)][ks * 32 + (lane >> 4) * 8];
        acc[fn] = __builtin_amdgcn_mfma_f32_16x16x32_bf16(a, b, acc[fn], 0, 0, 0);
      }
    }
  }
  int rbase = mt * 64 + wave * 16 + ((lane >> 4) << 2);
  int cb = nt * 64 + (lane & 15);
#pragma unroll
  for (int fn = 0; fn < 4; ++fn) {
    int col = cb + fn * 16;
    float bs = bias ? bias[col] : 0.0f;
#pragma unroll
    for (int r = 0; r < 4; ++r) {
      int row = rbase + r;
      if (row < M) {
        float val = acc[fn][r] + bs;
        if (f32out) Cf[(size_t)row * 512 + col] = val;
        else        Cb[(size_t)row * 512 + col] = f2bf(val);
      }
    }
  }
}

// ---------- fused relative attention ----------
// grid (16 ti-tiles, 8 heads, 8 batch), 256 threads (4 waves x 16 rows).
__global__ __launch_bounds__(256, 4) void attn_kernel(
    const unsigned short* __restrict__ QU,  // (B*T,512) bf16 = q+bq+u
    const unsigned short* __restrict__ QV,  // (B*T,512) bf16 = q+bq+v
    const unsigned short* __restrict__ K,   // (B*T,512) bf16
    const unsigned short* __restrict__ Vt,  // [b][h][d][s] bf16
    const unsigned short* __restrict__ P,   // (2047,512) bf16
    unsigned short* __restrict__ O) {       // (B*T,512) bf16
  __shared__ __align__(16) unsigned short k_s[64][72];
  __shared__ __align__(16) unsigned short vt_s[64][72];
  // dual use: window phase = [128 rows][stride 72];
  // raw/P phase = [64 rows][stride 136], col XOR-swizzled by ((row>>2)&3)<<4
  __shared__ __align__(16) unsigned short p_s[128 * 72];

  int tt = blockIdx.x, h = blockIdx.y, b = blockIdx.z;
  int t0 = tt * 64;
  int tid = threadIdx.x, lane = tid & 63, wave = tid >> 6;
  int lr = tid >> 2, lc = (tid & 3) << 4;
  int l15 = lane & 15, g = lane >> 4;
  int rowg = g << 2;

  // Q fragments straight from global (held in regs for the whole block)
  short8 aqu[2], aqv[2];
  {
    size_t qoff = (size_t)(b * 1024 + t0 + wave * 16 + l15) * 512 + h * 64 + g * 8;
    aqu[0] = *(const short8*)(QU + qoff);
    aqu[1] = *(const short8*)(QU + qoff + 32);
    aqv[0] = *(const short8*)(QV + qoff);
    aqv[1] = *(const short8*)(QV + qoff + 32);
  }

  const unsigned short* Kbase = K + (size_t)(b * 1024) * 512 + h * 64;
  const unsigned short* Vbase = Vt + (size_t)((b * 8 + h) * 64) * 1024;

  float4v accO[4] = {};
  float m_r[4] = {-1e30f, -1e30f, -1e30f, -1e30f};
  float l_r[4] = {0.f, 0.f, 0.f, 0.f};

  for (int st = 0; st < 16; ++st) {
    int s0 = st * 64;
    int w0 = s0 - t0 + 960;                 // first window row, in [0,1920]
    __syncthreads();                        // prev-iter LDS reads complete
    // stage K tile
    {
      const unsigned short* kp = Kbase + (size_t)(s0 + lr) * 512 + lc;
      *(uint4*)&k_s[lr][lc]     = *(const uint4*)kp;
      *(uint4*)&k_s[lr][lc + 8] = *(const uint4*)(kp + 8);
    }
    // stage V^T tile: vt_s[d][s] (vectorized, pre-transposed globally)
    {
      const unsigned short* vp = Vbase + (size_t)lr * 1024 + s0 + lc;
      *(uint4*)&vt_s[lr][lc]     = *(const uint4*)vp;
      *(uint4*)&vt_s[lr][lc + 8] = *(const uint4*)(vp + 8);
    }
    // stage pos window: 128 rows x 64
    {
      int r2 = tid >> 1, c2 = (tid & 1) << 5;
      int wr = w0 + r2; if (wr > 2046) wr = 2046;
      const unsigned short* pp = P + (size_t)wr * 512 + h * 64 + c2;
      unsigned short* dp = &p_s[r2 * 72 + c2];
      *(uint4*)dp        = *(const uint4*)pp;
      *(uint4*)(dp + 8)  = *(const uint4*)(pp + 8);
      *(uint4*)(dp + 16) = *(const uint4*)(pp + 16);
      *(uint4*)(dp + 24) = *(const uint4*)(pp + 24);
    }
    __syncthreads();

    // content (64x64, A=QU) and pos-window (64x128, A=QV) score MFMAs
    float4v accS[4] = {}; float4v accP[8] = {};
#pragma unroll
    for (int ks = 0; ks < 2; ++ks) {
#pragma unroll
      for (int fn = 0; fn < 4; ++fn) {
        short8 bk = *(const short8*)&k_s[fn * 16 + l15][ks * 32 + g * 8];
        accS[fn] = __builtin_amdgcn_mfma_f32_16x16x32_bf16(aqu[ks], bk, accS[fn], 0, 0, 0);
      }
#pragma unroll
      for (int fn = 0; fn < 8; ++fn) {
        short8 bp = *(const short8*)&p_s[(fn * 16 + l15) * 72 + ks * 32 + g * 8];
        accP[fn] = __builtin_amdgcn_mfma_f32_16x16x32_bf16(aqv[ks], bp, accP[fn], 0, 0, 0);
      }
    }
    __syncthreads();   // all waves done reading the window region

    // stage pos_raw rows (wave-local), col ^= ((row>>2)&3)<<4 == g<<4
#pragma unroll
    for (int fn = 0; fn < 8; ++fn)
#pragma unroll
      for (int r = 0; r < 4; ++r)
        p_s[(wave * 16 + rowg + r) * 136 + ((fn * 16 + l15) ^ (g << 4))] =
            f2bf(accP[fn][r]);

    // combine + online softmax (wave-local)
    float pvals[4][4]; float alpha[4];
#pragma unroll
    for (int r = 0; r < 4; ++r) {
      int tl = wave * 16 + rowg + r;        // block-local ti
      float sc[4]; float rowmax = -1e30f;
#pragma unroll
      for (int fn = 0; fn < 4; ++fn) {
        int si = fn * 16 + l15;
        int j = si - tl + 63;               // 0..126
        float s = (accS[fn][r] + bf2f(p_s[tl * 136 + (j ^ (g << 4))])) * 0.125f;
        sc[fn] = s;
        rowmax = fmaxf(rowmax, s);
      }
      rowmax = fmaxf(rowmax, __shfl_xor(rowmax, 1));
      rowmax = fmaxf(rowmax, __shfl_xor(rowmax, 2));
      rowmax = fmaxf(rowmax, __shfl_xor(rowmax, 4));
      rowmax = fmaxf(rowmax, __shfl_xor(rowmax, 8));
      float mnew = fmaxf(m_r[r], rowmax);
      float al = __expf(m_r[r] - mnew);
      float rs = 0.f;
#pragma unroll
      for (int fn = 0; fn < 4; ++fn) {
        float e = __expf(sc[fn] - mnew);
        pvals[fn][r] = e;
        rs += e;
      }
      rs += __shfl_xor(rs, 1); rs += __shfl_xor(rs, 2);
      rs += __shfl_xor(rs, 4); rs += __shfl_xor(rs, 8);
      l_r[r] = l_r[r] * al + rs;
      m_r[r] = mnew;
      alpha[r] = al;
    }
#pragma unroll
    for (int fn = 0; fn < 4; ++fn)
#pragma unroll
      for (int r = 0; r < 4; ++r) accO[fn][r] *= alpha[r];

    // stage P (bf16) into cols 0..63 of own rows (same swizzle)
#pragma unroll
    for (int fn = 0; fn < 4; ++fn)
#pragma unroll
      for (int r = 0; r < 4; ++r)
        p_s[(wave * 16 + rowg + r) * 136 + ((fn * 16 + l15) ^ (g << 4))] =
            f2bf(pvals[fn][r]);

    // PV: accO += P @ V   (A-frag from swizzled P rows, B-frag from vt_s)
#pragma unroll
    for (int ks = 0; ks < 2; ++ks) {
      int gr = l15 >> 2;
      int c0 = ks * 32 + g * 8;
      short8 ap = *(const short8*)&p_s[(wave * 16 + l15) * 136 + (c0 ^ (gr << 4))];
#pragma unroll
      for (int fn = 0; fn < 4; ++fn) {
        short8 bv = *(const short8*)&vt_s[fn * 16 + l15][ks * 32 + g * 8];
        accO[fn] = __builtin_amdgcn_mfma_f32_16x16x32_bf16(ap, bv, accO[fn], 0, 0, 0);
      }
    }
  }

  // epilogue: O / l -> bf16
#pragma unroll
  for (int fn = 0; fn < 4; ++fn) {
    int dcol = fn * 16 + l15;
#pragma unroll
    for (int r = 0; r < 4; ++r) {
      int row = t0 + wave * 16 + rowg + r;
      float o = accO[fn][r] / l_r[r];
      O[(size_t)(b * 1024 + row) * 512 + h * 64 + dcol] = f2bf(o);
    }
  }
}

// ---------- host ----------
extern "C" void kernel_launch(void* const* d_in, const int* in_sizes, int n_in,
                              void* d_out, int out_size, void* d_ws, size_t ws_size,
                              hipStream_t stream) {
  const float* x       = (const float*)d_in[0];
  const float* pos_emb = (const float*)d_in[1];
  const float* Wq      = (const float*)d_in[2];
  const float* bq      = (const float*)d_in[3];
  const float* Wk      = (const float*)d_in[4];
  const float* Wv      = (const float*)d_in[5];
  const float* Wp      = (const float*)d_in[6];
  const float* Wo      = (const float*)d_in[7];
  const float* bo      = (const float*)d_in[8];
  const float* u       = (const float*)d_in[9];
  const float* v       = (const float*)d_in[10];

  char* ws = (char*)d_ws;
  unsigned short* xb   = (unsigned short*)ws; ws += (size_t)8192 * 512 * 2;
  unsigned short* peb  = (unsigned short*)ws; ws += (size_t)2048 * 512 * 2;
  unsigned short* wqkv = (unsigned short*)ws; ws += (size_t)3 * 512 * 512 * 2; // wq|wk|wv ^T contiguous
  unsigned short* wpt  = (unsigned short*)ws; ws += (size_t)512 * 512 * 2;
  unsigned short* wot  = (unsigned short*)ws; ws += (size_t)512 * 512 * 2;
  unsigned short* qub  = (unsigned short*)ws; ws += (size_t)8192 * 512 * 2;
  unsigned short* qvb  = (unsigned short*)ws; ws += (size_t)8192 * 512 * 2;
  unsigned short* kb   = (unsigned short*)ws; ws += (size_t)8192 * 512 * 2;
  unsigned short* vtb  = (unsigned short*)ws; ws += (size_t)8192 * 512 * 2;
  unsigned short* pb   = (unsigned short*)ws; ws += (size_t)2048 * 512 * 2;
  unsigned short* attb = (unsigned short*)ws; ws += (size_t)8192 * 512 * 2;

  // conversions
  cvt_bf16_kernel<<<4096, 256, 0, stream>>>(x, xb, 1048576);
  cvt_bf16_kernel<<<1024, 256, 0, stream>>>(pos_emb, peb, 262016);
  transpose_cvt5_kernel<<<dim3(1024, 5), 256, 0, stream>>>(Wq, Wk, Wv, Wp, Wo, wqkv);
  // wqkv holds [Wq^T; Wk^T; Wv^T; Wp^T; Wo^T]; wpt/wot alias slots 3 and 4
  (void)wpt; (void)wot;
  unsigned short* wpt_p = wqkv + (size_t)3 * 262144;
  unsigned short* wot_p = wqkv + (size_t)4 * 262144;

  // merged QKV projection (+u/v fold, +V transpose)
  qkv_gemm_kernel<<<dim3(128, 24), 256, 0, stream>>>(xb, wqkv, bq, u, v,
                                                     qub, qvb, kb, vtb);
  // pos projection
  gemm_kernel<<<dim3(32, 8), 256, 0, stream>>>(peb, wpt_p, nullptr, pb, nullptr, 2047, 0);

  // fused attention
  attn_kernel<<<dim3(16, 8, 8), 256, 0, stream>>>(qub, qvb, kb, vtb, pb, attb);

  // output projection (f32 out)
  gemm_kernel<<<dim3(128, 8), 256, 0, stream>>>(attb, wot_p, bo, nullptr,
                                                (float*)d_out, 8192, 1);
}

// Round 3
// 171.497 us; speedup vs baseline: 1.4120x; 1.1026x over previous
//
#include <hip/hip_runtime.h>
#include <hip/hip_bf16.h>

// Relative (Transformer-XL) multi-head attention, MI355X gfx950.
// B=8, T=1024, H=8, d=64, D_MODEL=512, W=2047. Output f32.
//
// Round 3:
//  - relative-shift gather moved from LDS round-trip to in-register lane
//    rotation (ds_bpermute): frag = fn + (3-wave) + carry,
//    srcLane = (l15 - 4g - r - 1) & 15, carry = (l15 >= 4g+r+1)
//  - probs (P) staged into the window LDS region (stride 72, bank-floor
//    pattern) after a single mid barrier; stride-136 region deleted
//  - everything else (projections, V pre-transpose, epilogues) as round 2

typedef __attribute__((ext_vector_type(8))) short short8;
typedef __attribute__((ext_vector_type(4))) float float4v;

__device__ __forceinline__ unsigned short f2bf(float f) {
  union { float f; unsigned u; } x; x.f = f;
  unsigned r = x.u + 0x7FFFu + ((x.u >> 16) & 1u);
  return (unsigned short)(r >> 16);
}
__device__ __forceinline__ float bf2f(unsigned short b) {
  union { unsigned u; float f; } x; x.u = ((unsigned)b) << 16;
  return x.f;
}

// ---------- conversion kernels ----------
__global__ void cvt_bf16_kernel(const float* __restrict__ in,
                                unsigned short* __restrict__ out, int n4) {
  int i = blockIdx.x * blockDim.x + threadIdx.x;
  if (i < n4) {
    float4 f = ((const float4*)in)[i];
    ushort4 r;
    r.x = f2bf(f.x); r.y = f2bf(f.y); r.z = f2bf(f.z); r.w = f2bf(f.w);
    ((ushort4*)out)[i] = r;
  }
}

// 5x 512x512 transposes in one launch: dst is 5 contiguous 512x512 bf16 mats
__global__ void transpose_cvt5_kernel(const float* __restrict__ Wq,
                                      const float* __restrict__ Wk,
                                      const float* __restrict__ Wv,
                                      const float* __restrict__ Wp,
                                      const float* __restrict__ Wo,
                                      unsigned short* __restrict__ dst) {
  int y = blockIdx.y;
  const float* w = (y == 0) ? Wq : (y == 1) ? Wk : (y == 2) ? Wv : (y == 3) ? Wp : Wo;
  unsigned short* wt = dst + (size_t)y * 262144;
  int idx = blockIdx.x * 256 + threadIdx.x;
  int kk = idx >> 9, n = idx & 511;
  wt[(n << 9) | kk] = f2bf(w[idx]);
}

// ---------- merged QKV projection GEMM ----------
__global__ __launch_bounds__(256) void qkv_gemm_kernel(
    const unsigned short* __restrict__ A,
    const unsigned short* __restrict__ Bt,
    const float* __restrict__ bq,
    const float* __restrict__ uvec,
    const float* __restrict__ vvec,
    unsigned short* __restrict__ QU, unsigned short* __restrict__ QV,
    unsigned short* __restrict__ Kb, unsigned short* __restrict__ Vt) {
  __shared__ __align__(16) unsigned short As[64][72];
  __shared__ __align__(16) unsigned short Bs[64][72];
  int mt = blockIdx.x, nt = blockIdx.y;
  int tid = threadIdx.x;
  int lr = tid >> 2, lc = (tid & 3) << 4;
  int lane = tid & 63, wave = tid >> 6;
  int l15 = lane & 15, g = lane >> 4;

  const unsigned short* Ap = A + (size_t)(mt * 64 + lr) * 512 + lc;
  const unsigned short* Bp = Bt + (size_t)(nt * 64 + lr) * 512 + lc;

  float4v acc[4] = {};
  for (int kt = 0; kt < 8; ++kt) {
    __syncthreads();
    *(uint4*)&As[lr][lc]     = *(const uint4*)(Ap + kt * 64);
    *(uint4*)&As[lr][lc + 8] = *(const uint4*)(Ap + kt * 64 + 8);
    *(uint4*)&Bs[lr][lc]     = *(const uint4*)(Bp + kt * 64);
    *(uint4*)&Bs[lr][lc + 8] = *(const uint4*)(Bp + kt * 64 + 8);
    __syncthreads();
#pragma unroll
    for (int ks = 0; ks < 2; ++ks) {
      short8 a = *(const short8*)&As[wave * 16 + l15][ks * 32 + g * 8];
#pragma unroll
      for (int fn = 0; fn < 4; ++fn) {
        short8 b = *(const short8*)&Bs[fn * 16 + l15][ks * 32 + g * 8];
        acc[fn] = __builtin_amdgcn_mfma_f32_16x16x32_bf16(a, b, acc[fn], 0, 0, 0);
      }
    }
  }
  int rl = wave * 16 + ((lane >> 4) << 2);
  if (nt < 8) {
#pragma unroll
    for (int fn = 0; fn < 4; ++fn) {
      int col = nt * 64 + fn * 16 + l15;
      float bs = bq[col], uu = uvec[col], vv = vvec[col];
#pragma unroll
      for (int r = 0; r < 4; ++r) {
        size_t idx = (size_t)(mt * 64 + rl + r) * 512 + col;
        float base = acc[fn][r] + bs;
        QU[idx] = f2bf(base + uu);
        QV[idx] = f2bf(base + vv);
      }
    }
  } else if (nt < 16) {
#pragma unroll
    for (int fn = 0; fn < 4; ++fn) {
      int col = (nt - 8) * 64 + fn * 16 + l15;
#pragma unroll
      for (int r = 0; r < 4; ++r)
        Kb[(size_t)(mt * 64 + rl + r) * 512 + col] = f2bf(acc[fn][r]);
    }
  } else {
    __syncthreads();
#pragma unroll
    for (int fn = 0; fn < 4; ++fn)
#pragma unroll
      for (int r = 0; r < 4; ++r)
        As[rl + r][fn * 16 + l15] = f2bf(acc[fn][r]);
    __syncthreads();
    int d = tid >> 2, sc = (tid & 3) * 16;
    int bb = mt >> 4, s0 = (mt & 15) * 64, h = nt - 16;
    unsigned short tmp[16];
#pragma unroll
    for (int j = 0; j < 16; ++j) tmp[j] = As[sc + j][d];
    unsigned short* op = Vt + ((size_t)((bb * 8 + h) * 64 + d)) * 1024 + s0 + sc;
    *(uint4*)op       = *(uint4*)tmp;
    *(uint4*)(op + 8) = *(uint4*)(tmp + 8);
  }
}

// ---------- generic bf16 MFMA GEMM (pos projection, out projection) ----------
__global__ __launch_bounds__(256) void gemm_kernel(
    const unsigned short* __restrict__ A,
    const unsigned short* __restrict__ Bt,
    const float* __restrict__ bias,
    unsigned short* __restrict__ Cb,
    float* __restrict__ Cf,
    int M, int f32out) {
  __shared__ __align__(16) unsigned short As[64][72];
  __shared__ __align__(16) unsigned short Bs[64][72];
  int mt = blockIdx.x, nt = blockIdx.y;
  int tid = threadIdx.x;
  int lr = tid >> 2, lc = (tid & 3) << 4;
  int lane = tid & 63, wave = tid >> 6;

  int arow = mt * 64 + lr; if (arow >= M) arow = M - 1;
  const unsigned short* Ap = A + (size_t)arow * 512 + lc;
  const unsigned short* Bp = Bt + (size_t)(nt * 64 + lr) * 512 + lc;

  float4v acc[4] = {};
  for (int kt = 0; kt < 8; ++kt) {
    __syncthreads();
    *(uint4*)&As[lr][lc]     = *(const uint4*)(Ap + kt * 64);
    *(uint4*)&As[lr][lc + 8] = *(const uint4*)(Ap + kt * 64 + 8);
    *(uint4*)&Bs[lr][lc]     = *(const uint4*)(Bp + kt * 64);
    *(uint4*)&Bs[lr][lc + 8] = *(const uint4*)(Bp + kt * 64 + 8);
    __syncthreads();
#pragma unroll
    for (int ks = 0; ks < 2; ++ks) {
      short8 a = *(const short8*)&As[wave * 16 + (lane & 15)][ks * 32 + (lane >> 4) * 8];
#pragma unroll
      for (int fn = 0; fn < 4; ++fn) {
        short8 b = *(const short8*)&Bs[fn * 16 + (lane & 15)][ks * 32 + (lane >> 4) * 8];
        acc[fn] = __builtin_amdgcn_mfma_f32_16x16x32_bf16(a, b, acc[fn], 0, 0, 0);
      }
    }
  }
  int rbase = mt * 64 + wave * 16 + ((lane >> 4) << 2);
  int cb = nt * 64 + (lane & 15);
#pragma unroll
  for (int fn = 0; fn < 4; ++fn) {
    int col = cb + fn * 16;
    float bs = bias ? bias[col] : 0.0f;
#pragma unroll
    for (int r = 0; r < 4; ++r) {
      int row = rbase + r;
      if (row < M) {
        float val = acc[fn][r] + bs;
        if (f32out) Cf[(size_t)row * 512 + col] = val;
        else        Cb[(size_t)row * 512 + col] = f2bf(val);
      }
    }
  }
}

// ---------- fused relative attention ----------
// grid (16 ti-tiles, 8 heads, 8 batch), 256 threads (4 waves x 16 rows).
// Register-shuffle relative shift; probs staged through window LDS region.
#define SHIFT_C(C)                                                         \
  _Pragma("unroll")                                                        \
  for (int fn = 0; fn < 4; ++fn) {                                         \
    _Pragma("unroll")                                                      \
    for (int r = 0; r < 4; ++r) {                                          \
      int srcLane = (lane & 48) | ((l15 - 4 * g - r - 1) & 15);            \
      float v0 = __shfl(accP[fn + C][r], srcLane);                         \
      float v1 = __shfl(accP[fn + C + 1][r], srcLane);                     \
      float sh = (l15 >= 4 * g + r + 1) ? v1 : v0;                         \
      accS[fn][r] = (accS[fn][r] + sh) * 0.125f;                           \
    }                                                                      \
  }

__global__ __launch_bounds__(256, 4) void attn_kernel(
    const unsigned short* __restrict__ QU,  // (B*T,512) bf16 = q+bq+u
    const unsigned short* __restrict__ QV,  // (B*T,512) bf16 = q+bq+v
    const unsigned short* __restrict__ K,   // (B*T,512) bf16
    const unsigned short* __restrict__ Vt,  // [b][h][d][s] bf16
    const unsigned short* __restrict__ P,   // (2047,512) bf16
    unsigned short* __restrict__ O) {       // (B*T,512) bf16
  __shared__ __align__(16) unsigned short k_s[64][72];
  __shared__ __align__(16) unsigned short vt_s[64][72];
  // window phase: [128 rows][stride 72]; probs phase (post mid-barrier):
  // rows [wave*16 .. wave*16+15], cols 0..63, same stride 72 (wave-local)
  __shared__ __align__(16) unsigned short win_s[128 * 72];

  int tt = blockIdx.x, h = blockIdx.y, b = blockIdx.z;
  int t0 = tt * 64;
  int tid = threadIdx.x, lane = tid & 63, wave = tid >> 6;
  int lr = tid >> 2, lc = (tid & 3) << 4;
  int l15 = lane & 15, g = lane >> 4;
  int w16 = wave * 16;

  // Q fragments straight from global (held in regs for the whole block)
  short8 aqu[2], aqv[2];
  {
    size_t qoff = (size_t)(b * 1024 + t0 + w16 + l15) * 512 + h * 64 + g * 8;
    aqu[0] = *(const short8*)(QU + qoff);
    aqu[1] = *(const short8*)(QU + qoff + 32);
    aqv[0] = *(const short8*)(QV + qoff);
    aqv[1] = *(const short8*)(QV + qoff + 32);
  }

  const unsigned short* Kbase = K + (size_t)(b * 1024) * 512 + h * 64;
  const unsigned short* Vbase = Vt + (size_t)((b * 8 + h) * 64) * 1024;

  float4v accO[4] = {};
  float m_r[4] = {-1e30f, -1e30f, -1e30f, -1e30f};
  float l_r[4] = {0.f, 0.f, 0.f, 0.f};

  for (int st = 0; st < 16; ++st) {
    int s0 = st * 64;
    int w0 = s0 - t0 + 960;                 // first window row, in [0,1920]
    __syncthreads();                        // B1: prev-iter LDS reads done
    // stage K tile
    {
      const unsigned short* kp = Kbase + (size_t)(s0 + lr) * 512 + lc;
      *(uint4*)&k_s[lr][lc]     = *(const uint4*)kp;
      *(uint4*)&k_s[lr][lc + 8] = *(const uint4*)(kp + 8);
    }
    // stage V^T tile: vt_s[d][s]
    {
      const unsigned short* vp = Vbase + (size_t)lr * 1024 + s0 + lc;
      *(uint4*)&vt_s[lr][lc]     = *(const uint4*)vp;
      *(uint4*)&vt_s[lr][lc + 8] = *(const uint4*)(vp + 8);
    }
    // stage pos window: 128 rows x 64
    {
      int r2 = tid >> 1, c2 = (tid & 1) << 5;
      int wr = w0 + r2; if (wr > 2046) wr = 2046;
      const unsigned short* pp = P + (size_t)wr * 512 + h * 64 + c2;
      unsigned short* dp = &win_s[r2 * 72 + c2];
      *(uint4*)dp        = *(const uint4*)pp;
      *(uint4*)(dp + 8)  = *(const uint4*)(pp + 8);
      *(uint4*)(dp + 16) = *(const uint4*)(pp + 16);
      *(uint4*)(dp + 24) = *(const uint4*)(pp + 24);
    }
    __syncthreads();                        // B2: staging visible

    // content (64x64, A=QU) and pos-window (64x128, A=QV) score MFMAs
    float4v accS[4] = {}; float4v accP[8] = {};
#pragma unroll
    for (int ks = 0; ks < 2; ++ks) {
#pragma unroll
      for (int fn = 0; fn < 4; ++fn) {
        short8 bk = *(const short8*)&k_s[fn * 16 + l15][ks * 32 + g * 8];
        accS[fn] = __builtin_amdgcn_mfma_f32_16x16x32_bf16(aqu[ks], bk, accS[fn], 0, 0, 0);
      }
#pragma unroll
      for (int fn = 0; fn < 8; ++fn) {
        short8 bp = *(const short8*)&win_s[(fn * 16 + l15) * 72 + ks * 32 + g * 8];
        accP[fn] = __builtin_amdgcn_mfma_f32_16x16x32_bf16(aqv[ks], bp, accP[fn], 0, 0, 0);
      }
    }
    __syncthreads();                        // B3: window/k/v reads done

    // relative shift via in-register lane rotation:
    //   score(tl, si) needs accP value at window col j = si - tl + 63;
    //   within a 16-lane group tl = wave*16 + 4g + r is uniform ->
    //   frag = fn + (3-wave) + carry, srcLane l15' = (l15 - 4g - r - 1)&15
    if (wave == 0)      { SHIFT_C(3) }
    else if (wave == 1) { SHIFT_C(2) }
    else if (wave == 2) { SHIFT_C(1) }
    else                { SHIFT_C(0) }

    // online softmax (wave-local); probs written to win_s rows [w16..w16+15]
    float alpha[4];
#pragma unroll
    for (int r = 0; r < 4; ++r) {
      float rowmax = fmaxf(fmaxf(accS[0][r], accS[1][r]),
                           fmaxf(accS[2][r], accS[3][r]));
      rowmax = fmaxf(rowmax, __shfl_xor(rowmax, 1));
      rowmax = fmaxf(rowmax, __shfl_xor(rowmax, 2));
      rowmax = fmaxf(rowmax, __shfl_xor(rowmax, 4));
      rowmax = fmaxf(rowmax, __shfl_xor(rowmax, 8));
      float mnew = fmaxf(m_r[r], rowmax);
      float al = __expf(m_r[r] - mnew);
      float rs = 0.f;
#pragma unroll
      for (int fn = 0; fn < 4; ++fn) {
        float e = __expf(accS[fn][r] - mnew);
        win_s[(w16 + 4 * g + r) * 72 + fn * 16 + l15] = f2bf(e);
        rs += e;
      }
      rs += __shfl_xor(rs, 1); rs += __shfl_xor(rs, 2);
      rs += __shfl_xor(rs, 4); rs += __shfl_xor(rs, 8);
      l_r[r] = l_r[r] * al + rs;
      m_r[r] = mnew;
      alpha[r] = al;
    }
#pragma unroll
    for (int fn = 0; fn < 4; ++fn)
#pragma unroll
      for (int r = 0; r < 4; ++r) accO[fn][r] *= alpha[r];

    // PV: accO += P @ V  (A-frag: own probs rows; B-frag: vt_s)
#pragma unroll
    for (int ks = 0; ks < 2; ++ks) {
      short8 ap = *(const short8*)&win_s[(w16 + l15) * 72 + ks * 32 + g * 8];
#pragma unroll
      for (int fn = 0; fn < 4; ++fn) {
        short8 bv = *(const short8*)&vt_s[fn * 16 + l15][ks * 32 + g * 8];
        accO[fn] = __builtin_amdgcn_mfma_f32_16x16x32_bf16(ap, bv, accO[fn], 0, 0, 0);
      }
    }
  }

  // epilogue: O / l -> bf16
#pragma unroll
  for (int fn = 0; fn < 4; ++fn) {
    int dcol = fn * 16 + l15;
#pragma unroll
    for (int r = 0; r < 4; ++r) {
      int row = t0 + w16 + 4 * g + r;
      float o = accO[fn][r] / l_r[r];
      O[(size_t)(b * 1024 + row) * 512 + h * 64 + dcol] = f2bf(o);
    }
  }
}

// ---------- host ----------
extern "C" void kernel_launch(void* const* d_in, const int* in_sizes, int n_in,
                              void* d_out, int out_size, void* d_ws, size_t ws_size,
                              hipStream_t stream) {
  const float* x       = (const float*)d_in[0];
  const float* pos_emb = (const float*)d_in[1];
  const float* Wq      = (const float*)d_in[2];
  const float* bq      = (const float*)d_in[3];
  const float* Wk      = (const float*)d_in[4];
  const float* Wv      = (const float*)d_in[5];
  const float* Wp      = (const float*)d_in[6];
  const float* Wo      = (const float*)d_in[7];
  const float* bo      = (const float*)d_in[8];
  const float* u       = (const float*)d_in[9];
  const float* v       = (const float*)d_in[10];

  char* ws = (char*)d_ws;
  unsigned short* xb   = (unsigned short*)ws; ws += (size_t)8192 * 512 * 2;
  unsigned short* peb  = (unsigned short*)ws; ws += (size_t)2048 * 512 * 2;
  unsigned short* wqkv = (unsigned short*)ws; ws += (size_t)5 * 512 * 512 * 2;
  unsigned short* qub  = (unsigned short*)ws; ws += (size_t)8192 * 512 * 2;
  unsigned short* qvb  = (unsigned short*)ws; ws += (size_t)8192 * 512 * 2;
  unsigned short* kb   = (unsigned short*)ws; ws += (size_t)8192 * 512 * 2;
  unsigned short* vtb  = (unsigned short*)ws; ws += (size_t)8192 * 512 * 2;
  unsigned short* pb   = (unsigned short*)ws; ws += (size_t)2048 * 512 * 2;
  unsigned short* attb = (unsigned short*)ws; ws += (size_t)8192 * 512 * 2;

  cvt_bf16_kernel<<<4096, 256, 0, stream>>>(x, xb, 1048576);
  cvt_bf16_kernel<<<1024, 256, 0, stream>>>(pos_emb, peb, 262016);
  transpose_cvt5_kernel<<<dim3(1024, 5), 256, 0, stream>>>(Wq, Wk, Wv, Wp, Wo, wqkv);
  unsigned short* wpt_p = wqkv + (size_t)3 * 262144;
  unsigned short* wot_p = wqkv + (size_t)4 * 262144;

  qkv_gemm_kernel<<<dim3(128, 24), 256, 0, stream>>>(xb, wqkv, bq, u, v,
                                                     qub, qvb, kb, vtb);
  gemm_kernel<<<dim3(32, 8), 256, 0, stream>>>(peb, wpt_p, nullptr, pb, nullptr, 2047, 0);

  attn_kernel<<<dim3(16, 8, 8), 256, 0, stream>>>(qub, qvb, kb, vtb, pb, attb);

  gemm_kernel<<<dim3(128, 8), 256, 0, stream>>>(attb, wot_p, bo, nullptr,
                                                (float*)d_out, 8192, 1);
}